// Round 21
// baseline (446.102 us; speedup 1.0000x reference)
//
#include <hip/hip_runtime.h>
#include <math.h>

#define N_NODES_C 100000
#define N_EDGES_C 3200000
// D_NODE=16, D_EDGE=8, D_HIDDEN=16

#define NORM_MSG_TP 0.08838834764831845f   // 1/sqrt(16*8)
#define NORM_UPD_TP 0.0625f                // 1/sqrt(16*16)
#define NORM_LIN    0.25f                  // 1/sqrt(16)

#define NBUK  782      // buckets of 128 nodes
#define NBUKP 784
#define BPB   8000     // edges per bucketize block: 3.2M/8000 = 400 exact
#define NBLK_BUK 400
#define SPLIT 4        // sub-blocks per bucket in bagg7

typedef float f32x4 __attribute__((ext_vector_type(4)));
typedef short bf16x8 __attribute__((ext_vector_type(8)));
typedef int   int4v  __attribute__((ext_vector_type(4)));

__device__ __forceinline__ float silu_f(float v) {
  return v / (1.0f + __expf(-v));
}

__device__ __forceinline__ void atomic_add_hw(float* p, float v) {
  unsafeAtomicAdd(p, v);
}

__device__ __forceinline__ unsigned int bf16_bits(float f) {
  unsigned int b = __float_as_uint(f);
  return (b + 0x7fffu + ((b >> 16) & 1u)) >> 16;
}
__device__ __forceinline__ unsigned int pack_bf16x2(float lo, float hi) {
  return bf16_bits(lo) | (bf16_bits(hi) << 16);
}
__device__ __forceinline__ float unlo(unsigned int w) { return __uint_as_float(w << 16); }
__device__ __forceinline__ float unhi(unsigned int w) { return __uint_as_float(w & 0xffff0000u); }

// ---------------- bucketize ----------------

__global__ __launch_bounds__(256) void bucketize_kernel(
    const int* __restrict__ row,
    int* __restrict__ bids, int* __restrict__ sct)
{
  __shared__ int lhist[NBUKP];
  __shared__ int lcur[NBUKP];
  __shared__ int partial[256];
  __shared__ int lids[BPB];
  const int t = threadIdx.x;
  const int base = blockIdx.x * BPB;

  for (int i = t; i < NBUKP; i += 256) lhist[i] = 0;
  __syncthreads();
  for (int k = t; k < BPB; k += 256)
    atomicAdd(&lhist[row[base + k] >> 7], 1);
  __syncthreads();

  int csum = 0;
  if (t < 196) {
    int s = 0;
#pragma unroll
    for (int j = 0; j < 4; ++j) {
      const int v = lhist[t * 4 + j];
      lhist[t * 4 + j] = s;
      s += v;
    }
    csum = s;
  }
  partial[t] = csum;
  __syncthreads();
  for (int o = 1; o < 256; o <<= 1) {
    int tv = (t >= o) ? partial[t - o] : 0;
    __syncthreads();
    partial[t] += tv;
    __syncthreads();
  }
  const int add = partial[t] - csum;
  if (t < 196) {
#pragma unroll
    for (int j = 0; j < 4; ++j) lhist[t * 4 + j] += add;
  }
  __syncthreads();
  for (int i = t; i < NBUKP; i += 256) lcur[i] = lhist[i];
  __syncthreads();

  for (int k = t; k < BPB; k += 256) {
    const int r = row[base + k];
    const int b = r >> 7;
    const int p = atomicAdd(&lcur[b], 1);
    lids[p] = ((base + k) << 7) | (r & 127);
  }
  __syncthreads();

  for (int i = t; i < NBUKP; i += 256)
    sct[blockIdx.x * NBUKP + i] = lhist[i];
  for (int k = t; k < BPB; k += 256)
    bids[base + k] = lids[k];
}

// ---------------- colscan ----------------

__global__ __launch_bounds__(256) void colscan_kernel(
    const int* __restrict__ sct, int* __restrict__ colpre, int* __restrict__ btot) {
  __shared__ int sa[512], sb[512];
  const int t = threadIdx.x;
  const int b = blockIdx.x;
  const int c0 = (t < NBLK_BUK)
      ? sct[t * NBUKP + b + 1] - sct[t * NBUKP + b] : 0;
  const int c1 = (t + 256 < NBLK_BUK)
      ? sct[(t + 256) * NBUKP + b + 1] - sct[(t + 256) * NBUKP + b] : 0;
  sa[t] = c0; sa[t + 256] = c1;
  int* src = sa; int* dst = sb;
  for (int o = 1; o < 512; o <<= 1) {
    __syncthreads();
    dst[t]       = src[t]       + ((t >= o) ? src[t - o] : 0);
    dst[t + 256] = src[t + 256] + ((t + 256 >= o) ? src[t + 256 - o] : 0);
    int* tmp = src; src = dst; dst = tmp;
  }
  __syncthreads();
  if (t < NBLK_BUK) colpre[t * NBUKP + b] = src[t] - c0;
  if (t + 256 < NBLK_BUK) colpre[(t + 256) * NBUKP + b] = src[t + 256] - c1;
  if (t == 0) btot[b] = src[NBLK_BUK - 1];
}

// ---------------- generic scans ----------------

__global__ __launch_bounds__(256) void scan_block(
    const int* __restrict__ cnt, int* __restrict__ off, int* __restrict__ bsum, int n) {
  __shared__ int s[256];
  const int t = threadIdx.x;
  const int i = blockIdx.x * 256 + t;
  const int v = (i < n) ? cnt[i] : 0;
  s[t] = v;
  __syncthreads();
#pragma unroll
  for (int o = 1; o < 256; o <<= 1) {
    int tv = (t >= o) ? s[t - o] : 0;
    __syncthreads();
    s[t] += tv;
    __syncthreads();
  }
  if (i < n) off[i] = s[t] - v;
  if (t == 255) bsum[blockIdx.x] = s[255];
}

__global__ void scan_bsum(int* __restrict__ bsum, int nb) {
  __shared__ int s[512];
  const int t = threadIdx.x;
  const int v = (t < nb) ? bsum[t] : 0;
  s[t] = v;
  __syncthreads();
#pragma unroll
  for (int o = 1; o < 512; o <<= 1) {
    int tv = (t >= o) ? s[t - o] : 0;
    __syncthreads();
    s[t] += tv;
    __syncthreads();
  }
  if (t < nb) bsum[t] = s[t] - v;
}

__global__ __launch_bounds__(256) void scan_add(
    int* __restrict__ off, const int* __restrict__ bsum, int n, int total) {
  int i = blockIdx.x * 256 + threadIdx.x;
  if (i < n) off[i] += bsum[blockIdx.x];
  if (i == 0) off[n] = total;
}

// ---------------- bscatter2 ----------------

__global__ __launch_bounds__(256) void bscatter2_kernel(
    const int* __restrict__ bids, const int* __restrict__ sct,
    const int* __restrict__ colpre, const int* __restrict__ boff,
    const int* __restrict__ eidx, const float* __restrict__ ea,
    int* __restrict__ cl, uint4* __restrict__ eab) {
  __shared__ int srow[NBUKP];
  __shared__ int crow[NBUKP];
  const int t = threadIdx.x;
  const int blk = blockIdx.x;
  for (int i = t; i < NBUKP; i += 256) {
    srow[i] = sct[blk * NBUKP + i];
    crow[i] = colpre[blk * NBUKP + i];
  }
  __syncthreads();
  for (int k = t; k < BPB; k += 256) {
    const int code = bids[blk * BPB + k];
    const int eid = code >> 7;
    const int local = code & 127;
    int lo = 0, hi = 783;
    while (hi - lo > 1) {
      const int mid = (lo + hi) >> 1;
      if (srow[mid] <= k) lo = mid; else hi = mid;
    }
    const int slot = boff[lo] + crow[lo] + (k - srow[lo]);
    const int col = eidx[N_EDGES_C + eid];
    cl[slot] = (local << 20) | col;
    const float4 a = *reinterpret_cast<const float4*>(ea + (size_t)eid * 8);
    const float4 b = *reinterpret_cast<const float4*>(ea + (size_t)eid * 8 + 4);
    uint4 w;
    w.x = pack_bf16x2(a.x, a.y);
    w.y = pack_bf16x2(a.z, a.w);
    w.z = pack_bf16x2(b.x, b.y);
    w.w = pack_bf16x2(b.z, b.w);
    eab[slot] = w;
  }
}

// ---------------- x -> bf16 table ----------------

__global__ __launch_bounds__(256) void xcast_kernel(
    const float* __restrict__ x, unsigned short* __restrict__ xb) {
  const int i = blockIdx.x * 256 + threadIdx.x;
  if (i < N_NODES_C * 2) {
    const float4 a = *reinterpret_cast<const float4*>(x + (size_t)i * 8);
    const float4 b = *reinterpret_cast<const float4*>(x + (size_t)i * 8 + 4);
    uint4 w;
    w.x = pack_bf16x2(a.x, a.y); w.y = pack_bf16x2(a.z, a.w);
    w.z = pack_bf16x2(b.x, b.y); w.w = pack_bf16x2(b.z, b.w);
    *reinterpret_cast<uint4*>(xb + (size_t)i * 8) = w;
  }
}

__global__ void zero_f4(float4* __restrict__ p, int n4) {
  int i = blockIdx.x * blockDim.x + threadIdx.x;
  if (i < n4) p[i] = make_float4(0.f, 0.f, 0.f, 0.f);
}

// ---------------- bagg7: fused MFMA aggregation, DISJOINT partial outputs ----------------
// Same loop as bagg6 (flipped mfma: C[row=edge][col=h]); merge is now plain
// coalesced nt stores into per-sub partial buffers -- ZERO global atomics.

__global__ __launch_bounds__(512) void bagg7_kernel(
    const int* __restrict__ boff,     // [NBUK+1]
    const int* __restrict__ cl,       // [E] (local<<20)|col at sorted slot
    const uint4* __restrict__ eab,    // [E] bf16x8 ea at sorted slot
    const unsigned short* __restrict__ xb,  // [N,16] bf16
    const float* __restrict__ Wtp,    // [16,8,16]
    float* __restrict__ aggpart)      // [SPLIT][N][16] partial raw sums
{
  __shared__ float lagg[128][17];
  const int t = threadIdx.x;
  const int b   = blockIdx.x >> 2;    // bucket
  const int sub = blockIdx.x & 3;     // sub-block
  for (int i = t; i < 128 * 17; i += 512) (&lagg[0][0])[i] = 0.f;
  __syncthreads();

  const int lane  = t & 63;
  const int wv    = t >> 6;           // 8 waves
  const int el    = lane & 15;
  const int g     = lane >> 4;
  const int gsel  = g >> 1;
  const int ghalf = g & 1;

  // B frag (constant W): bq[q][tt] = Wtp[i=8*ghalf+tt][j=2q+gsel][h=el] (k=j*16+i)
  bf16x8 bq[4];
#pragma unroll
  for (int q = 0; q < 4; ++q) {
#pragma unroll
    for (int tt = 0; tt < 8; ++tt) {
      const float w = Wtp[(8 * ghalf + tt) * 128 + (2 * q + gsel) * 16 + el];
      bq[q][tt] = (short)bf16_bits(w);
    }
  }

  const int p0 = boff[b];
  const int p1 = boff[b + 1];

  for (int sbase = p0 + (sub * 8 + wv) * 16; sbase < p1; sbase += 32 * 16) {
    const int s = sbase + el;
    const bool ok = (s < p1);
    const int clv = ok ? cl[s] : 0;
    const int col = clv & 0xFFFFF;
    uint4 ev;
    if (ok) ev = eab[s];
    else { ev.x = ev.y = ev.z = ev.w = 0; }
    const uint4 xh = *reinterpret_cast<const uint4*>(
        xb + (size_t)col * 16 + 8 * ghalf);

    float xf[8];
    xf[0] = unlo(xh.x); xf[1] = unhi(xh.x);
    xf[2] = unlo(xh.y); xf[3] = unhi(xh.y);
    xf[4] = unlo(xh.z); xf[5] = unhi(xh.z);
    xf[6] = unlo(xh.w); xf[7] = unhi(xh.w);
    float eq[4];
    eq[0] = gsel ? unhi(ev.x) : unlo(ev.x);
    eq[1] = gsel ? unhi(ev.y) : unlo(ev.y);
    eq[2] = gsel ? unhi(ev.z) : unlo(ev.z);
    eq[3] = gsel ? unhi(ev.w) : unlo(ev.w);

    f32x4 acc = {0.f, 0.f, 0.f, 0.f};
#pragma unroll
    for (int q = 0; q < 4; ++q) {
      const float e_ = eq[q];
      const unsigned u0 = __float_as_uint(xf[0] * e_) + 0x8000u;
      const unsigned u1 = __float_as_uint(xf[1] * e_) + 0x8000u;
      const unsigned u2 = __float_as_uint(xf[2] * e_) + 0x8000u;
      const unsigned u3 = __float_as_uint(xf[3] * e_) + 0x8000u;
      const unsigned u4 = __float_as_uint(xf[4] * e_) + 0x8000u;
      const unsigned u5 = __float_as_uint(xf[5] * e_) + 0x8000u;
      const unsigned u6 = __float_as_uint(xf[6] * e_) + 0x8000u;
      const unsigned u7 = __float_as_uint(xf[7] * e_) + 0x8000u;
      int4v iv;
      iv.x = (int)__builtin_amdgcn_perm(u1, u0, 0x07060302u);
      iv.y = (int)__builtin_amdgcn_perm(u3, u2, 0x07060302u);
      iv.z = (int)__builtin_amdgcn_perm(u5, u4, 0x07060302u);
      iv.w = (int)__builtin_amdgcn_perm(u7, u6, 0x07060302u);
      union { int4v i; bf16x8 h; } cv; cv.i = iv;
      acc = __builtin_amdgcn_mfma_f32_16x16x32_bf16(cv.h, bq[q], acc, 0, 0, 0);
    }

    // acc[reg] = m[edge = sbase+4g+reg][h = el]
#pragma unroll
    for (int reg = 0; reg < 4; ++reg) {
      const int ee = 4 * g + reg;
      if (sbase + ee < p1) {
        const int loc = __shfl(clv, ee, 16) >> 20;
        atomicAdd(&lagg[loc][el], silu_f(acc[reg] * NORM_MSG_TP));
      }
    }
  }
  __syncthreads();

  // plain coalesced nt stores into this sub-block's private partial buffer
#pragma unroll
  for (int i = 0; i < 4; ++i) {
    const int idx = t * 4 + i;        // 0..2047
    const int node = idx >> 4, k2 = idx & 15;
    const int n = b * 128 + node;
    if (n < N_NODES_C)
      __builtin_nontemporal_store(
          lagg[node][k2],
          &aggpart[((size_t)sub * N_NODES_C + n) * 16 + k2]);
  }
}

// ---------------- node update (partial-sum + Wlin fused) ----------------

__global__ __launch_bounds__(256) void node_kernel3(
    const float* __restrict__ x, const float* __restrict__ aggpart,
    const float* __restrict__ Wmlin,  // [16,16] W_msg_lin
    const float* __restrict__ Wtp,    // [16,16,16] W_upd_tp
    const float* __restrict__ Wlin,   // [16,16]   W_upd_lin
    float* __restrict__ out)
{
  __shared__ float sW[4096];
  __shared__ float sM[256];
  __shared__ float sL[256];
  for (int t = threadIdx.x; t < 4096; t += 256) sW[t] = Wtp[t];
  sM[threadIdx.x] = Wmlin[threadIdx.x];
  sL[threadIdx.x] = Wlin[threadIdx.x];
  __syncthreads();

  const long n = (long)blockIdx.x * 256 + threadIdx.x;
  if (n >= N_NODES_C) return;

  float xr[16], araw[16], ar[16];
  const float4* xp = reinterpret_cast<const float4*>(x + (size_t)n * 16);
#pragma unroll
  for (int q = 0; q < 4; ++q) {
    float4 v = xp[q];
    xr[q*4+0] = v.x; xr[q*4+1] = v.y; xr[q*4+2] = v.z; xr[q*4+3] = v.w;
  }
#pragma unroll
  for (int j = 0; j < 16; ++j) araw[j] = 0.f;
#pragma unroll
  for (int sub = 0; sub < SPLIT; ++sub) {
    const float4* ap = reinterpret_cast<const float4*>(
        aggpart + ((size_t)sub * N_NODES_C + n) * 16);
#pragma unroll
    for (int q = 0; q < 4; ++q) {
      float4 w = ap[q];
      araw[q*4+0] += w.x; araw[q*4+1] += w.y;
      araw[q*4+2] += w.z; araw[q*4+3] += w.w;
    }
  }
  // agg = NORM_LIN * araw @ Wmlin
#pragma unroll
  for (int h2 = 0; h2 < 16; ++h2) {
    float a = 0.f;
#pragma unroll
    for (int h = 0; h < 16; ++h) a = fmaf(araw[h], sM[h * 16 + h2], a);
    ar[h2] = a * NORM_LIN;
  }

  float u[16];
#pragma unroll
  for (int k = 0; k < 16; ++k) u[k] = 0.f;
#pragma unroll
  for (int i = 0; i < 16; ++i) {
#pragma unroll
    for (int h = 0; h < 16; ++h) {
      const float p = xr[i] * ar[h];
      const float* w = &sW[(i*16 + h) * 16];
#pragma unroll
      for (int k = 0; k < 16; ++k) u[k] = fmaf(p, w[k], u[k]);
    }
  }
  float g[16];
#pragma unroll
  for (int k = 0; k < 16; ++k) g[k] = silu_f(u[k] * NORM_UPD_TP);
  float res[16];
#pragma unroll
  for (int k2 = 0; k2 < 16; ++k2) {
    float a = 0.f;
#pragma unroll
    for (int k = 0; k < 16; ++k) a = fmaf(g[k], sL[k*16 + k2], a);
    res[k2] = xr[k2] + a * NORM_LIN;
  }
  float4* op = reinterpret_cast<float4*>(out + (size_t)n * 16);
#pragma unroll
  for (int q = 0; q < 4; ++q)
    op[q] = make_float4(res[q*4+0], res[q*4+1], res[q*4+2], res[q*4+3]);
}

// ---------------- Tier C fallback: atomic scatter ----------------

#define EPT 2
__global__ __launch_bounds__(256) void edge_kernel(
    const float* __restrict__ x, const float* __restrict__ ea,
    const float* __restrict__ Wtp, const float* __restrict__ Wlin,
    const int* __restrict__ eidx, float* __restrict__ agg)
{
  __shared__ float sW[2048];
  __shared__ float sL[256];
  for (int t = threadIdx.x; t < 2048; t += 256) sW[t] = Wtp[t];
  sL[threadIdx.x] = Wlin[threadIdx.x];
  __syncthreads();
  const long e0 = ((long)blockIdx.x * 256 + threadIdx.x) * EPT;
  float xr[EPT][16], er[EPT][8];
  int rw[EPT];
#pragma unroll
  for (int e = 0; e < EPT; ++e) {
    const long ei = e0 + e;
    const int c = eidx[N_EDGES_C + ei];
    rw[e] = eidx[ei];
    const float4* xp = reinterpret_cast<const float4*>(x + (size_t)c * 16);
#pragma unroll
    for (int q = 0; q < 4; ++q) {
      float4 v = xp[q];
      xr[e][q*4+0] = v.x; xr[e][q*4+1] = v.y; xr[e][q*4+2] = v.z; xr[e][q*4+3] = v.w;
    }
    const float4* ep = reinterpret_cast<const float4*>(ea + (size_t)ei * 8);
#pragma unroll
    for (int q = 0; q < 2; ++q) {
      float4 v = ep[q];
      er[e][q*4+0] = v.x; er[e][q*4+1] = v.y; er[e][q*4+2] = v.z; er[e][q*4+3] = v.w;
    }
  }
  float m[EPT][16];
#pragma unroll
  for (int e = 0; e < EPT; ++e)
#pragma unroll
    for (int h = 0; h < 16; ++h) m[e][h] = 0.f;
#pragma unroll
  for (int i = 0; i < 16; ++i) {
#pragma unroll
    for (int j = 0; j < 8; ++j) {
      float p[EPT];
#pragma unroll
      for (int e = 0; e < EPT; ++e) p[e] = xr[e][i] * er[e][j];
      const float* w = &sW[(i*8 + j) * 16];
#pragma unroll
      for (int h = 0; h < 16; ++h) {
        const float wv = w[h];
#pragma unroll
        for (int e = 0; e < EPT; ++e) m[e][h] = fmaf(p[e], wv, m[e][h]);
      }
    }
  }
#pragma unroll
  for (int e = 0; e < EPT; ++e) {
    float g[16];
#pragma unroll
    for (int h = 0; h < 16; ++h) g[h] = silu_f(m[e][h] * NORM_MSG_TP);
    float* ap = agg + (size_t)rw[e] * 16;
#pragma unroll
    for (int h2 = 0; h2 < 16; ++h2) {
      float a = 0.f;
#pragma unroll
      for (int h = 0; h < 16; ++h) a = fmaf(g[h], sL[h*16 + h2], a);
      atomic_add_hw(ap + h2, a * NORM_LIN);
    }
  }
}

__global__ __launch_bounds__(256) void node_kernel(
    const float* __restrict__ x, const float* __restrict__ agg,
    const float* __restrict__ Wtp, const float* __restrict__ Wlin,
    float* __restrict__ out)
{
  __shared__ float sW[4096];
  __shared__ float sL[256];
  for (int t = threadIdx.x; t < 4096; t += 256) sW[t] = Wtp[t];
  sL[threadIdx.x] = Wlin[threadIdx.x];
  __syncthreads();

  const long n = (long)blockIdx.x * 256 + threadIdx.x;
  if (n >= N_NODES_C) return;

  float xr[16], ar[16];
  const float4* xp = reinterpret_cast<const float4*>(x + (size_t)n * 16);
  const float4* ap = reinterpret_cast<const float4*>(agg + (size_t)n * 16);
#pragma unroll
  for (int q = 0; q < 4; ++q) {
    float4 v = xp[q];
    xr[q*4+0] = v.x; xr[q*4+1] = v.y; xr[q*4+2] = v.z; xr[q*4+3] = v.w;
    float4 w = ap[q];
    ar[q*4+0] = w.x; ar[q*4+1] = w.y; ar[q*4+2] = w.z; ar[q*4+3] = w.w;
  }
  float u[16];
#pragma unroll
  for (int k = 0; k < 16; ++k) u[k] = 0.f;
#pragma unroll
  for (int i = 0; i < 16; ++i) {
#pragma unroll
    for (int h = 0; h < 16; ++h) {
      const float p = xr[i] * ar[h];
      const float* w = &sW[(i*16 + h) * 16];
#pragma unroll
      for (int k = 0; k < 16; ++k) u[k] = fmaf(p, w[k], u[k]);
    }
  }
  float g[16];
#pragma unroll
  for (int k = 0; k < 16; ++k) g[k] = silu_f(u[k] * NORM_UPD_TP);
  float res[16];
#pragma unroll
  for (int k2 = 0; k2 < 16; ++k2) {
    float a = 0.f;
#pragma unroll
    for (int k = 0; k < 16; ++k) a = fmaf(g[k], sL[k*16 + k2], a);
    res[k2] = xr[k2] + a * NORM_LIN;
  }
  float4* op = reinterpret_cast<float4*>(out + (size_t)n * 16);
#pragma unroll
  for (int q = 0; q < 4; ++q)
    op[q] = make_float4(res[q*4+0], res[q*4+1], res[q*4+2], res[q*4+3]);
}

// ---------------- launch ----------------

extern "C" void kernel_launch(void* const* d_in, const int* in_sizes, int n_in,
                              void* d_out, int out_size, void* d_ws, size_t ws_size,
                              hipStream_t stream) {
  const float* node_features = (const float*)d_in[0];
  const float* edge_attr     = (const float*)d_in[1];
  const float* W_msg_tp      = (const float*)d_in[3];
  const float* W_msg_lin     = (const float*)d_in[4];
  const float* W_upd_tp      = (const float*)d_in[5];
  const float* W_upd_lin     = (const float*)d_in[6];
  const int*   edge_index    = (const int*)d_in[7];
  float* out = (float*)d_out;
  char* ws = (char*)d_ws;

  const int NB_N = (N_NODES_C + 255) / 256;           // 391
  const int NB_E = N_EDGES_C / 256;                   // 12500 exact

  // ---- Tier A11: sorted-payload radix + fused agg, disjoint partials (108.1 MB) ----
  const size_t A_SCT   = 0;
  const size_t A_COLP  = 1254400;
  const size_t A_BTOT  = 2508800;
  const size_t A_BOFF  = 2512000;
  const size_t A_BSUM  = 2515200;
  const size_t A_BIDS  = 2517248;                     // E ints (dead after bscatter2)
  const size_t A_CL    = A_BIDS + 12800000;           // E ints
  const size_t A_EAB   = A_CL + 12800000;             // E uint4
  const size_t A_XB    = A_EAB + 51200000;            // N*16 ushort
  const size_t A_PART  = A_XB + 3200000;              // SPLIT*N*16 floats (25.6 MB)
  const size_t A_NEED  = A_PART + (size_t)SPLIT * N_NODES_C * 16 * 4;  // 108,117,248

  if (ws_size >= A_NEED) {
    int* sct   = (int*)(ws + A_SCT);
    int* colp  = (int*)(ws + A_COLP);
    int* btot  = (int*)(ws + A_BTOT);
    int* boff  = (int*)(ws + A_BOFF);
    int* bsum  = (int*)(ws + A_BSUM);
    int* bids  = (int*)(ws + A_BIDS);
    int* cl    = (int*)(ws + A_CL);
    uint4* eab = (uint4*)(ws + A_EAB);
    unsigned short* xb = (unsigned short*)(ws + A_XB);
    float* aggpart = (float*)(ws + A_PART);

    hipLaunchKernelGGL(bucketize_kernel, dim3(NBLK_BUK), dim3(256), 0, stream,
                       edge_index, bids, sct);
    hipLaunchKernelGGL(colscan_kernel, dim3(NBUK), dim3(256), 0, stream,
                       sct, colp, btot);
    hipLaunchKernelGGL(scan_block, dim3((NBUK + 255) / 256), dim3(256), 0, stream,
                       btot, boff, bsum, NBUK);
    hipLaunchKernelGGL(scan_bsum, dim3(1), dim3(512), 0, stream,
                       bsum, (NBUK + 255) / 256);
    hipLaunchKernelGGL(scan_add, dim3((NBUK + 255) / 256), dim3(256), 0, stream,
                       boff, bsum, NBUK, N_EDGES_C);
    hipLaunchKernelGGL(bscatter2_kernel, dim3(NBLK_BUK), dim3(256), 0, stream,
                       bids, sct, colp, boff, edge_index, edge_attr, cl, eab);
    hipLaunchKernelGGL(xcast_kernel, dim3((N_NODES_C * 2 + 255) / 256), dim3(256),
                       0, stream, node_features, xb);
    hipLaunchKernelGGL(bagg7_kernel, dim3(NBUK * SPLIT), dim3(512), 0, stream,
                       boff, cl, eab, xb, W_msg_tp, aggpart);
    hipLaunchKernelGGL(node_kernel3, dim3(NB_N), dim3(256), 0, stream,
                       node_features, aggpart, W_msg_lin, W_upd_tp, W_upd_lin, out);
  } else {
    float* agg = (float*)ws;
    const int n4 = N_NODES_C * 16 / 4;
    hipLaunchKernelGGL(zero_f4, dim3((n4 + 255) / 256), dim3(256), 0, stream,
                       (float4*)agg, n4);
    hipLaunchKernelGGL(edge_kernel, dim3(N_EDGES_C / (256 * EPT)), dim3(256), 0, stream,
                       node_features, edge_attr, W_msg_tp, W_msg_lin, edge_index, agg);
    hipLaunchKernelGGL(node_kernel, dim3(NB_N), dim3(256), 0, stream,
                       node_features, agg, W_upd_tp, W_upd_lin, out);
  }
}

// Round 22
// 399.950 us; speedup vs baseline: 1.1154x; 1.1154x over previous
//
#include <hip/hip_runtime.h>
#include <math.h>

#define N_NODES_C 100000
#define N_EDGES_C 3200000
// D_NODE=16, D_EDGE=8, D_HIDDEN=16

#define NORM_MSG_TP 0.08838834764831845f   // 1/sqrt(16*8)
#define NORM_UPD_TP 0.0625f                // 1/sqrt(16*16)
#define NORM_LIN    0.25f                  // 1/sqrt(16)

typedef float f32x4 __attribute__((ext_vector_type(4)));
typedef short bf16x8 __attribute__((ext_vector_type(8)));
typedef int   int4v  __attribute__((ext_vector_type(4)));

__device__ __forceinline__ float silu_f(float v) {
  return v / (1.0f + __expf(-v));
}

__device__ __forceinline__ void atomic_add_hw(float* p, float v) {
  unsafeAtomicAdd(p, v);
}

// float -> bf16 bits (round to nearest even)
__device__ __forceinline__ unsigned int bf16_bits(float f) {
  unsigned int b = __float_as_uint(f);
  return (b + 0x7fffu + ((b >> 16) & 1u)) >> 16;
}
__device__ __forceinline__ unsigned int pack_bf16x2(float lo, float hi) {
  return bf16_bits(lo) | (bf16_bits(hi) << 16);
}
__device__ __forceinline__ float unlo(unsigned int w) { return __uint_as_float(w << 16); }
__device__ __forceinline__ float unhi(unsigned int w) { return __uint_as_float(w & 0xffff0000u); }

// ---------------- CSR build ----------------

__global__ __launch_bounds__(256) void zero_ints(int* __restrict__ p, int n) {
  int i = blockIdx.x * 256 + threadIdx.x;
  if (i < n) p[i] = 0;
}

// returning histogram: pos[e] = 0-based rank of edge e within its dest row
__global__ __launch_bounds__(256) void hist_kernel(
    const int* __restrict__ row, int* __restrict__ cnt, int* __restrict__ pos) {
  int e = blockIdx.x * 256 + threadIdx.x;   // grid exact: E/256
  pos[e] = atomicAdd(&cnt[row[e]], 1);
}

__global__ __launch_bounds__(256) void scan_block(
    const int* __restrict__ cnt, int* __restrict__ off, int* __restrict__ bsum, int n) {
  __shared__ int s[256];
  const int t = threadIdx.x;
  const int i = blockIdx.x * 256 + t;
  const int v = (i < n) ? cnt[i] : 0;
  s[t] = v;
  __syncthreads();
#pragma unroll
  for (int o = 1; o < 256; o <<= 1) {
    int tv = (t >= o) ? s[t - o] : 0;
    __syncthreads();
    s[t] += tv;
    __syncthreads();
  }
  if (i < n) off[i] = s[t] - v;
  if (t == 255) bsum[blockIdx.x] = s[255];
}

__global__ void scan_bsum(int* __restrict__ bsum, int nb) {
  __shared__ int s[512];
  const int t = threadIdx.x;
  const int v = (t < nb) ? bsum[t] : 0;
  s[t] = v;
  __syncthreads();
#pragma unroll
  for (int o = 1; o < 512; o <<= 1) {
    int tv = (t >= o) ? s[t - o] : 0;
    __syncthreads();
    s[t] += tv;
    __syncthreads();
  }
  if (t < nb) bsum[t] = s[t] - v;
}

__global__ __launch_bounds__(256) void scan_add(
    int* __restrict__ off, const int* __restrict__ bsum, int n, int total) {
  int i = blockIdx.x * 256 + threadIdx.x;
  if (i < n) off[i] += bsum[blockIdx.x];
  if (i == 0) off[n] = total;
}

// ---------------- x -> bf16 table (3.2 MB, L2-resident) ----------------

__global__ __launch_bounds__(256) void xcast_kernel(
    const float* __restrict__ x, unsigned short* __restrict__ xb) {
  const int i = blockIdx.x * 256 + threadIdx.x;   // one thread per 8 elems
  if (i < N_NODES_C * 2) {
    const float4 a = *reinterpret_cast<const float4*>(x + (size_t)i * 8);
    const float4 b = *reinterpret_cast<const float4*>(x + (size_t)i * 8 + 4);
    uint4 w;
    w.x = pack_bf16x2(a.x, a.y); w.y = pack_bf16x2(a.z, a.w);
    w.z = pack_bf16x2(b.x, b.y); w.w = pack_bf16x2(b.z, b.w);
    *reinterpret_cast<uint4*>(xb + (size_t)i * 8) = w;
  }
}

// ---------------- place4: pipelined MFMA message + sorted scatter (no atomics) ----------------
// Slot p = off[row] + pos[e] (precomputed by returning hist): the claim chain is
// two cheap reads. 2-deep pipeline on the eidx -> xb chain. nt scatter store.

#define CLAIM_TILE(T, CC, PP) do {                                   \
    const int e_ = (T) * 16 + r;                                     \
    if (g == 0) {                                                    \
      CC = eidx[N_EDGES_C + e_];                                     \
      PP = off[eidx[e_]] + pos[e_];                                  \
    }                                                                \
  } while (0)

#define GATH_TILE(T, CC, XH, F4) do {                                \
    const int e_ = (T) * 16 + r;                                     \
    const int c_ = __shfl(CC, r);                                    \
    if (g < 2) {                                                     \
      XH = *reinterpret_cast<const uint4*>(xb + (size_t)c_ * 16 + g * 8); \
      F4 = *reinterpret_cast<const float4*>(ea + (size_t)e_ * 8 + g * 4); \
    }                                                                \
  } while (0)

__global__ __launch_bounds__(256) void place4_kernel(
    const int*   __restrict__ eidx,   // [2,E]
    const float* __restrict__ ea,     // [E,8] fp32
    const float* __restrict__ Wtp,    // [16,8,16]
    const int*   __restrict__ off,    // [N+1]
    const int*   __restrict__ pos,    // [E] rank within row
    const unsigned short* __restrict__ xb,  // [N,16] bf16
    unsigned int* __restrict__ msort) // [E*8] words: slot p = 32B bf16x16
{
  __shared__ float sm[4][16][20];     // stride 20: 16B-aligned rows, 2-way banks
  const int lane  = threadIdx.x & 63;
  const int wv    = threadIdx.x >> 6;
  const int r     = lane & 15;
  const int g     = lane >> 4;
  const int gsel  = g >> 1;
  const int ghalf = g & 1;

  // B frag: bq[q][t] = Wtp[i=8*ghalf+t][j=2q+gsel][h=r]  (K reordered k=j*16+i)
  bf16x8 bq[4];
#pragma unroll
  for (int q = 0; q < 4; ++q) {
#pragma unroll
    for (int t = 0; t < 8; ++t) {
      const float w = Wtp[(8 * ghalf + t) * 128 + (2 * q + gsel) * 16 + r];
      bq[q][t] = (short)bf16_bits(w);
    }
  }

  const int s = gridDim.x * 4;
  const int wid = blockIdx.x * 4 + wv;
  const int ntiles = N_EDGES_C / 16;  // 200000

  int cc_a = 0, pp_a = 0, cc_b = 0, pp_b = 0;
  uint4 xh_a; xh_a.x = xh_a.y = xh_a.z = xh_a.w = 0;
  float4 f4_a = make_float4(0.f, 0.f, 0.f, 0.f);

  if (wid < ntiles)     CLAIM_TILE(wid, cc_a, pp_a);
  if (wid + s < ntiles) CLAIM_TILE(wid + s, cc_b, pp_b);
  if (wid < ntiles)     GATH_TILE(wid, cc_a, xh_a, f4_a);

  for (int t = wid; t < ntiles; t += s) {
    // depth-2 prefetch: slot + column index
    int cc_c = 0, pp_c = 0;
    if (t + 2 * s < ntiles) CLAIM_TILE(t + 2 * s, cc_c, pp_c);
    // depth-1 prefetch: gathers
    uint4 xh_b; xh_b.x = xh_b.y = xh_b.z = xh_b.w = 0;
    float4 f4_b = make_float4(0.f, 0.f, 0.f, 0.f);
    if (t + s < ntiles) GATH_TILE(t + s, cc_b, xh_b, f4_b);

    // ---- compute tile t ----
    uint4 xh;
    xh.x = (unsigned)__shfl((int)xh_a.x, ghalf * 16 + r);
    xh.y = (unsigned)__shfl((int)xh_a.y, ghalf * 16 + r);
    xh.z = (unsigned)__shfl((int)xh_a.z, ghalf * 16 + r);
    xh.w = (unsigned)__shfl((int)xh_a.w, ghalf * 16 + r);
    float xf[8];
    xf[0] = unlo(xh.x); xf[1] = unhi(xh.x);
    xf[2] = unlo(xh.y); xf[3] = unhi(xh.y);
    xf[4] = unlo(xh.z); xf[5] = unhi(xh.z);
    xf[6] = unlo(xh.w); xf[7] = unhi(xh.w);
    const float a0 = __shfl(f4_a.x, r),      a1 = __shfl(f4_a.y, r);
    const float a2 = __shfl(f4_a.z, r),      a3 = __shfl(f4_a.w, r);
    const float b0 = __shfl(f4_a.x, 16 + r), b1 = __shfl(f4_a.y, 16 + r);
    const float b2 = __shfl(f4_a.z, 16 + r), b3 = __shfl(f4_a.w, 16 + r);
    float eq[4];
    eq[0] = gsel ? a1 : a0;  eq[1] = gsel ? a3 : a2;
    eq[2] = gsel ? b1 : b0;  eq[3] = gsel ? b3 : b2;

    f32x4 acc = {0.f, 0.f, 0.f, 0.f};
#pragma unroll
    for (int q = 0; q < 4; ++q) {
      const float e_ = eq[q];
      const unsigned u0 = __float_as_uint(xf[0] * e_) + 0x8000u;
      const unsigned u1 = __float_as_uint(xf[1] * e_) + 0x8000u;
      const unsigned u2 = __float_as_uint(xf[2] * e_) + 0x8000u;
      const unsigned u3 = __float_as_uint(xf[3] * e_) + 0x8000u;
      const unsigned u4 = __float_as_uint(xf[4] * e_) + 0x8000u;
      const unsigned u5 = __float_as_uint(xf[5] * e_) + 0x8000u;
      const unsigned u6 = __float_as_uint(xf[6] * e_) + 0x8000u;
      const unsigned u7 = __float_as_uint(xf[7] * e_) + 0x8000u;
      int4v iv;
      iv.x = (int)__builtin_amdgcn_perm(u1, u0, 0x07060302u);
      iv.y = (int)__builtin_amdgcn_perm(u3, u2, 0x07060302u);
      iv.z = (int)__builtin_amdgcn_perm(u5, u4, 0x07060302u);
      iv.w = (int)__builtin_amdgcn_perm(u7, u6, 0x07060302u);
      union { int4v i; bf16x8 h; } cv; cv.i = iv;
      acc = __builtin_amdgcn_mfma_f32_16x16x32_bf16(cv.h, bq[q], acc, 0, 0, 0);
    }

    // silu + 16x16 transpose via padded per-wave LDS tile
#pragma unroll
    for (int j2 = 0; j2 < 4; ++j2)
      sm[wv][g * 4 + j2][r] = silu_f(acc[j2] * NORM_MSG_TP);

    asm volatile("s_waitcnt lgkmcnt(0)" ::: "memory");
    __builtin_amdgcn_sched_barrier(0);

    const int rr  = lane >> 2;
    const int wsl = lane & 3;
    const float4 v4 = *reinterpret_cast<const float4*>(&sm[wv][rr][wsl * 4]);
    const int prr = __shfl(pp_a, rr);
    const unsigned long long wout =
        (unsigned long long)pack_bf16x2(v4.x, v4.y) |
        ((unsigned long long)pack_bf16x2(v4.z, v4.w) << 32);
    // nt store: bypass L2 allocation (cross-XCD line thrash), stream to L3
    __builtin_nontemporal_store(
        wout, reinterpret_cast<unsigned long long*>(&msort[(size_t)prr * 8 + wsl * 2]));

    // rotate pipeline state
    pp_a = pp_b; xh_a = xh_b; f4_a = f4_b;
    cc_b = cc_c; pp_b = pp_c;
  }
}

// ---------------- agg3: linear segment-sum of sorted messages + Wlin ----------------

__global__ __launch_bounds__(256) void agg3_kernel(
    const float* __restrict__ Wlin,   // [16,16]
    const unsigned int* __restrict__ msort,  // [E*8]
    const int*   __restrict__ off,    // [N+1]
    float*       __restrict__ agg)    // [N,16]
{
  __shared__ float sL[256];
  if (threadIdx.x < 256) sL[threadIdx.x] = Wlin[threadIdx.x];
  __syncthreads();

  const int slane = threadIdx.x & 15;
  const int n = blockIdx.x * 16 + (threadIdx.x >> 4);   // grid exact: N/16

  const int off0 = off[n];
  const int off1 = off[n + 1];

  float acc = 0.f;
  for (int p = off0; p < off1; ++p) {
    const unsigned int w = msort[(size_t)p * 8 + (slane >> 1)];
    acc += (slane & 1) ? unhi(w) : unlo(w);
  }

  float a = 0.f;
#pragma unroll
  for (int h = 0; h < 16; ++h) {
    const float v = __shfl(acc, h, 16);
    a = fmaf(v, sL[h * 16 + slane], a);
  }
  agg[(size_t)n * 16 + slane] = a * NORM_LIN;
}

// ---------------- node update ----------------

__global__ __launch_bounds__(256) void node_kernel(
    const float* __restrict__ x, const float* __restrict__ agg,
    const float* __restrict__ Wtp, const float* __restrict__ Wlin,
    float* __restrict__ out)
{
  __shared__ float sW[4096];
  __shared__ float sL[256];
  for (int t = threadIdx.x; t < 4096; t += 256) sW[t] = Wtp[t];
  sL[threadIdx.x] = Wlin[threadIdx.x];
  __syncthreads();

  const long n = (long)blockIdx.x * 256 + threadIdx.x;
  if (n >= N_NODES_C) return;

  float xr[16], ar[16];
  const float4* xp = reinterpret_cast<const float4*>(x + (size_t)n * 16);
  const float4* ap = reinterpret_cast<const float4*>(agg + (size_t)n * 16);
#pragma unroll
  for (int q = 0; q < 4; ++q) {
    float4 v = xp[q];
    xr[q*4+0] = v.x; xr[q*4+1] = v.y; xr[q*4+2] = v.z; xr[q*4+3] = v.w;
    float4 w = ap[q];
    ar[q*4+0] = w.x; ar[q*4+1] = w.y; ar[q*4+2] = w.z; ar[q*4+3] = w.w;
  }
  float u[16];
#pragma unroll
  for (int k = 0; k < 16; ++k) u[k] = 0.f;
#pragma unroll
  for (int i = 0; i < 16; ++i) {
#pragma unroll
    for (int h = 0; h < 16; ++h) {
      const float p = xr[i] * ar[h];
      const float* w = &sW[(i*16 + h) * 16];
#pragma unroll
      for (int k = 0; k < 16; ++k) u[k] = fmaf(p, w[k], u[k]);
    }
  }
  float g[16];
#pragma unroll
  for (int k = 0; k < 16; ++k) g[k] = silu_f(u[k] * NORM_UPD_TP);
  float res[16];
#pragma unroll
  for (int k2 = 0; k2 < 16; ++k2) {
    float a = 0.f;
#pragma unroll
    for (int k = 0; k < 16; ++k) a = fmaf(g[k], sL[k*16 + k2], a);
    res[k2] = xr[k2] + a * NORM_LIN;
  }
  float4* op = reinterpret_cast<float4*>(out + (size_t)n * 16);
#pragma unroll
  for (int q = 0; q < 4; ++q)
    op[q] = make_float4(res[q*4+0], res[q*4+1], res[q*4+2], res[q*4+3]);
}

// ---------------- Tier C fallback: atomic scatter ----------------

__global__ void zero_f4(float4* __restrict__ p, int n4) {
  int i = blockIdx.x * blockDim.x + threadIdx.x;
  if (i < n4) p[i] = make_float4(0.f, 0.f, 0.f, 0.f);
}

#define EPT 2
__global__ __launch_bounds__(256) void edge_kernel(
    const float* __restrict__ x, const float* __restrict__ ea,
    const float* __restrict__ Wtp, const float* __restrict__ Wlin,
    const int* __restrict__ eidx, float* __restrict__ agg)
{
  __shared__ float sW[2048];
  __shared__ float sL[256];
  for (int t = threadIdx.x; t < 2048; t += 256) sW[t] = Wtp[t];
  sL[threadIdx.x] = Wlin[threadIdx.x];
  __syncthreads();
  const long e0 = ((long)blockIdx.x * 256 + threadIdx.x) * EPT;
  float xr[EPT][16], er[EPT][8];
  int rw[EPT];
#pragma unroll
  for (int e = 0; e < EPT; ++e) {
    const long ei = e0 + e;
    const int c = eidx[N_EDGES_C + ei];
    rw[e] = eidx[ei];
    const float4* xp = reinterpret_cast<const float4*>(x + (size_t)c * 16);
#pragma unroll
    for (int q = 0; q < 4; ++q) {
      float4 v = xp[q];
      xr[e][q*4+0] = v.x; xr[e][q*4+1] = v.y; xr[e][q*4+2] = v.z; xr[e][q*4+3] = v.w;
    }
    const float4* ep = reinterpret_cast<const float4*>(ea + (size_t)ei * 8);
#pragma unroll
    for (int q = 0; q < 2; ++q) {
      float4 v = ep[q];
      er[e][q*4+0] = v.x; er[e][q*4+1] = v.y; er[e][q*4+2] = v.z; er[e][q*4+3] = v.w;
    }
  }
  float m[EPT][16];
#pragma unroll
  for (int e = 0; e < EPT; ++e)
#pragma unroll
    for (int h = 0; h < 16; ++h) m[e][h] = 0.f;
#pragma unroll
  for (int i = 0; i < 16; ++i) {
#pragma unroll
    for (int j = 0; j < 8; ++j) {
      float p[EPT];
#pragma unroll
      for (int e = 0; e < EPT; ++e) p[e] = xr[e][i] * er[e][j];
      const float* w = &sW[(i*8 + j) * 16];
#pragma unroll
      for (int h = 0; h < 16; ++h) {
        const float wv = w[h];
#pragma unroll
        for (int e = 0; e < EPT; ++e) m[e][h] = fmaf(p[e], wv, m[e][h]);
      }
    }
  }
#pragma unroll
  for (int e = 0; e < EPT; ++e) {
    float g[16];
#pragma unroll
    for (int h = 0; h < 16; ++h) g[h] = silu_f(m[e][h] * NORM_MSG_TP);
    float* ap = agg + (size_t)rw[e] * 16;
#pragma unroll
    for (int h2 = 0; h2 < 16; ++h2) {
      float a = 0.f;
#pragma unroll
      for (int h = 0; h < 16; ++h) a = fmaf(g[h], sL[h*16 + h2], a);
      atomic_add_hw(ap + h2, a * NORM_LIN);
    }
  }
}

// ---------------- launch ----------------

extern "C" void kernel_launch(void* const* d_in, const int* in_sizes, int n_in,
                              void* d_out, int out_size, void* d_ws, size_t ws_size,
                              hipStream_t stream) {
  const float* node_features = (const float*)d_in[0];
  const float* edge_attr     = (const float*)d_in[1];
  const float* W_msg_tp      = (const float*)d_in[3];
  const float* W_msg_lin     = (const float*)d_in[4];
  const float* W_upd_tp      = (const float*)d_in[5];
  const float* W_upd_lin     = (const float*)d_in[6];
  const int*   edge_index    = (const int*)d_in[7];
  float* out = (float*)d_out;
  char* ws = (char*)d_ws;

  const int NB_N = (N_NODES_C + 255) / 256;           // 391
  const int NB_E = N_EDGES_C / 256;                   // 12500 exact
  const int NB_G = N_NODES_C / 16;                    // 6250 exact

  // ---- Tier A4: fused MFMA msort, no-atomic place (119.2 MB) ----
  // pos dies after place4; agg (6.4 MB) aliases its region.
  const size_t A_OFF  = 0;                            // (N+1) ints
  const size_t A_CNT  = 400128;                       // N ints
  const size_t A_BSUM = 800256;                       // 512 ints
  const size_t A_POS  = 802304;                       // E ints (12.8 MB); agg aliases
  const size_t A_MSORT= A_POS + 12800000;             // E*8 uint (102.4 MB)
  const size_t A_XB   = A_MSORT + 102400000;          // N*16 ushort (3.2 MB)
  const size_t A_NEED = A_XB + 3200000;               // 119,202,304 B

  if (ws_size >= A_NEED) {
    int*   off   = (int*)(ws + A_OFF);
    int*   cnt   = (int*)(ws + A_CNT);
    int*   bsum  = (int*)(ws + A_BSUM);
    int*   pos   = (int*)(ws + A_POS);
    unsigned int* msort = (unsigned int*)(ws + A_MSORT);
    unsigned short* xb  = (unsigned short*)(ws + A_XB);
    float* agg   = (float*)(ws + A_POS);              // alias: pos dead after place4

    hipLaunchKernelGGL(zero_ints, dim3(NB_N), dim3(256), 0, stream, cnt, N_NODES_C);
    hipLaunchKernelGGL(hist_kernel, dim3(NB_E), dim3(256), 0, stream,
                       edge_index, cnt, pos);
    hipLaunchKernelGGL(scan_block, dim3(NB_N), dim3(256), 0, stream,
                       cnt, off, bsum, N_NODES_C);
    hipLaunchKernelGGL(scan_bsum, dim3(1), dim3(512), 0, stream, bsum, NB_N);
    hipLaunchKernelGGL(scan_add, dim3(NB_N), dim3(256), 0, stream,
                       off, bsum, N_NODES_C, N_EDGES_C);
    hipLaunchKernelGGL(xcast_kernel, dim3((N_NODES_C * 2 + 255) / 256), dim3(256),
                       0, stream, node_features, xb);
    hipLaunchKernelGGL(place4_kernel, dim3(2048), dim3(256), 0, stream,
                       edge_index, edge_attr, W_msg_tp, off, pos, xb, msort);
    hipLaunchKernelGGL(agg3_kernel, dim3(NB_G), dim3(256), 0, stream,
                       W_msg_lin, msort, off, agg);
    hipLaunchKernelGGL(node_kernel, dim3(NB_N), dim3(256), 0, stream,
                       node_features, agg, W_upd_tp, W_upd_lin, out);
  } else {
    float* agg = (float*)ws;
    const int n4 = N_NODES_C * 16 / 4;
    hipLaunchKernelGGL(zero_f4, dim3((n4 + 255) / 256), dim3(256), 0, stream,
                       (float4*)agg, n4);
    hipLaunchKernelGGL(edge_kernel, dim3(N_EDGES_C / (256 * EPT)), dim3(256), 0, stream,
                       node_features, edge_attr, W_msg_tp, W_msg_lin, edge_index, agg);
    hipLaunchKernelGGL(node_kernel, dim3(NB_N), dim3(256), 0, stream,
                       node_features, agg, W_upd_tp, W_upd_lin, out);
  }
}